// Round 5
// baseline (46.832 us; speedup 1.0000x reference)
//
#include <hip/hip_runtime.h>
#include <math.h>

namespace {
constexpr int N_TOK = 16384;
constexpr int DIM   = 1024;
constexpr int NCLAN = 32;
constexpr int FPC_  = 64;
constexpr int HID   = 128;            // 2*FPC
constexpr int FTOT  = NCLAN * FPC_;   // 2048
constexpr int ROWS  = 4;              // rows per fused block
constexpr float EPS = 1e-5f;
typedef float f4 __attribute__((ext_vector_type(4)));
}

// ---------------- pass 1: per-token argmax -> am[], global min -> sel ----------------
__global__ void routing_kernel(const float* __restrict__ xc, int* __restrict__ sel,
                               int* __restrict__ am) {
    const int i = blockIdx.x * blockDim.x + threadIdx.x;   // one thread per token
    const f4* row4 = (const f4*)(xc + (size_t)i * NCLAN);
    float best = -INFINITY; int bi = 0;
    #pragma unroll
    for (int q = 0; q < NCLAN / 4; ++q) {
        f4 v = row4[q];
        #pragma unroll
        for (int j = 0; j < 4; ++j) {
            float f = v[j];
            if (f > best) { best = f; bi = q * 4 + j; }
        }
    }
    am[i] = bi;
    int mn = bi;
    #pragma unroll
    for (int off = 32; off > 0; off >>= 1) mn = min(mn, __shfl_down(mn, off));
    if ((threadIdx.x & 63) == 0) atomicMin(sel, mn);
}

// ---------------- expert MLP body (block-uniform call, 256 threads) ----------------
__device__ __forceinline__ void expert_compute(
    int tok, int sel,
    const float* __restrict__ x,
    const float* __restrict__ W1, const float* __restrict__ b1,
    const float* __restrict__ gamma, const float* __restrict__ beta,
    const float* __restrict__ W2, const float* __restrict__ b2,
    float* __restrict__ xs, f4* __restrict__ part4, f4* __restrict__ hbuf4,
    f4* __restrict__ rbuf4, f4* __restrict__ obuf4, float* __restrict__ red)
{
    const int t = threadIdx.x;
    // stage x row: 256 threads x float4 = 4KB
    ((f4*)xs)[t] = ((const f4*)(x + (size_t)tok * DIM))[t];
    __syncthreads();

    // GEMV1: 32 ch-quads x 8 d-chunks; 128 f4 loads/thread, deep ILP
    {
        const int q = t & 31, c = t >> 5;
        const float* __restrict__ w1base = W1 + (size_t)sel * DIM * HID;
        f4 acc = {0.f, 0.f, 0.f, 0.f};
        const int d0 = c * (DIM / 8);
        #pragma unroll 8
        for (int d = d0; d < d0 + DIM / 8; ++d) {
            f4 w = ((const f4*)(w1base + (size_t)d * HID))[q];
            const float xv = xs[d];
            acc.x = fmaf(xv, w.x, acc.x);
            acc.y = fmaf(xv, w.y, acc.y);
            acc.z = fmaf(xv, w.z, acc.z);
            acc.w = fmaf(xv, w.w, acc.w);
        }
        part4[t] = acc;
    }
    __syncthreads();

    // reduce 8 chunks -> h quad; LN stats via wave-0 shfl
    if (t < 32) {
        f4 h = part4[t];
        #pragma unroll
        for (int k = 1; k < 8; ++k) {
            f4 p = part4[t + 32 * k];
            h.x += p.x; h.y += p.y; h.z += p.z; h.w += p.w;
        }
        f4 bb = ((const f4*)(b1 + sel * HID))[t];
        h.x += bb.x; h.y += bb.y; h.z += bb.z; h.w += bb.w;
        hbuf4[t] = h;
        float s  = h.x + h.y + h.z + h.w;
        float sq = h.x * h.x + h.y * h.y + h.z * h.z + h.w * h.w;
        #pragma unroll
        for (int off = 16; off > 0; off >>= 1) {
            s  += __shfl_down(s, off);
            sq += __shfl_down(sq, off);
        }
        if (t == 0) { red[0] = s; red[1] = sq; }
    }
    __syncthreads();

    // LayerNorm + ReLU
    if (t < 32) {
        const float mu  = red[0] * (1.0f / HID);
        const float msq = red[1] * (1.0f / HID);
        const float inv = rsqrtf(msq - mu * mu + EPS);
        f4 h = hbuf4[t];
        f4 g = ((const f4*)(gamma + sel * HID))[t];
        f4 b = ((const f4*)(beta  + sel * HID))[t];
        f4 r;
        r.x = fmaxf((h.x - mu) * inv * g.x + b.x, 0.f);
        r.y = fmaxf((h.y - mu) * inv * g.y + b.y, 0.f);
        r.z = fmaxf((h.z - mu) * inv * g.z + b.z, 0.f);
        r.w = fmaxf((h.w - mu) * inv * g.w + b.w, 0.f);
        rbuf4[t] = r;
    }
    __syncthreads();

    // GEMV2: 16 f-quads x 16 h-chunks of 8
    {
        const int fq = t & 15, hc = t >> 4;
        const float* __restrict__ w2base = W2 + (size_t)sel * HID * FPC_;
        const float* __restrict__ rb = (const float*)rbuf4;
        f4 acc = {0.f, 0.f, 0.f, 0.f};
        #pragma unroll 8
        for (int h = hc * 8; h < hc * 8 + 8; ++h) {
            f4 w = ((const f4*)(w2base + (size_t)h * FPC_))[fq];
            const float rv = rb[h];
            acc.x = fmaf(rv, w.x, acc.x);
            acc.y = fmaf(rv, w.y, acc.y);
            acc.z = fmaf(rv, w.z, acc.z);
            acc.w = fmaf(rv, w.w, acc.w);
        }
        part4[t] = acc;
    }
    __syncthreads();

    if (t < 16) {
        f4 o = part4[t];
        #pragma unroll
        for (int k = 1; k < 16; ++k) {
            f4 p = part4[t + 16 * k];
            o.x += p.x; o.y += p.y; o.z += p.z; o.w += p.w;
        }
        f4 bb = ((const f4*)(b2 + sel * FPC_))[t];
        o.x += bb.x; o.y += bb.y; o.z += bb.z; o.w += bb.w;
        obuf4[t] = o;
    }
    __syncthreads();
}

// ---------------- pass 2: fused zero-fill + expert, ROWS rows per block ----------------
__global__ __launch_bounds__(256) void fused_kernel(
    const float* __restrict__ x,
    const float* __restrict__ W1, const float* __restrict__ b1,
    const float* __restrict__ gamma, const float* __restrict__ beta,
    const float* __restrict__ W2, const float* __restrict__ b2,
    const int* __restrict__ sel_p, const int* __restrict__ am,
    float* __restrict__ out)
{
    __shared__ float xs[DIM];
    __shared__ f4    part4[256];
    __shared__ f4    hbuf4[HID/4];
    __shared__ f4    rbuf4[HID/4];
    __shared__ f4    obuf4[FPC_/4];
    __shared__ float red[2];

    const int t    = threadIdx.x;
    const int sel  = *sel_p;                 // uniform scalar load
    const int row0 = blockIdx.x * ROWS;

    // prefetch routing for all rows up-front (uniform -> scalar loads)
    int amv[ROWS];
    #pragma unroll
    for (int i = 0; i < ROWS; ++i) amv[i] = am[row0 + i];

    const f4 z = {0.f, 0.f, 0.f, 0.f};
    const int blk_lo = sel * (FPC_ / 4);     // first f4 index of the expert column block

    #pragma unroll 1
    for (int i = 0; i < ROWS; ++i) {
        const int tok = row0 + i;
        f4* __restrict__ orow = (f4*)(out + (size_t)tok * FTOT);
        if (amv[i] != sel) {                 // block-uniform branch
            orow[t]       = z;               // fire-and-forget, pipelines across rows
            orow[t + 256] = z;
        } else {
            expert_compute(tok, sel, x, W1, b1, gamma, beta, W2, b2,
                           xs, part4, hbuf4, rbuf4, obuf4, red);
            #pragma unroll
            for (int k = 0; k < 2; ++k) {
                const int p = t + k * 256;
                f4 v = z;
                if (p >= blk_lo && p < blk_lo + (FPC_ / 4)) v = obuf4[p - blk_lo];
                orow[p] = v;
            }
            __syncthreads();                 // obuf4 reuse safety for a later selected row
        }
    }
}

extern "C" void kernel_launch(void* const* d_in, const int* in_sizes, int n_in,
                              void* d_out, int out_size, void* d_ws, size_t ws_size,
                              hipStream_t stream) {
    const float* x     = (const float*)d_in[0];
    const float* xc    = (const float*)d_in[1];
    const float* W1    = (const float*)d_in[2];
    const float* b1    = (const float*)d_in[3];
    const float* gamma = (const float*)d_in[4];
    const float* beta  = (const float*)d_in[5];
    const float* W2    = (const float*)d_in[6];
    const float* b2    = (const float*)d_in[7];
    float* out = (float*)d_out;

    int* wsi   = (int*)d_ws;
    int* sel_p = wsi;          // scalar clan index
    int* am    = wsi + 2;      // per-token argmax, 64KB

    hipMemsetAsync(sel_p, 0x7f, sizeof(int), stream);   // sel = huge (poison 0xAA.. is negative!)
    routing_kernel<<<N_TOK / 256, 256, 0, stream>>>(xc, sel_p, am);
    fused_kernel<<<N_TOK / ROWS, 256, 0, stream>>>(x, W1, b1, gamma, beta, W2, b2,
                                                   sel_p, am, out);
}